// Round 1
// baseline (1267.207 us; speedup 1.0000x reference)
//
#include <hip/hip_runtime.h>
#include <hip/hip_bf16.h>
#include <math.h>

#define N_NODES 4096
#define FDIM 512
#define D 64
#define H 8
#define NWORDS (N_NODES / 64)   // 64 u64 words per adjacency row

// ---------------------------------------------------------------- adj -> bitmask
__global__ void k_bits(const int* __restrict__ adj, unsigned long long* __restrict__ bits) {
    int idx = blockIdx.x * 256 + threadIdx.x;          // element index i*N + j
    unsigned long long m = __ballot(adj[idx] != 0);    // 64-bit wave mask
    if ((threadIdx.x & 63) == 0) bits[idx >> 6] = m;
}

// ---------------------------------------------------------------- GEMM  [N,512] @ [512,64] per head
// grid: (N/64, heads); block 256. Each thread: 4 rows x 4 cols register tile.
__global__ void k_gemm(const float* __restrict__ X, const float* __restrict__ Wt,
                       float* __restrict__ Out) {
    const int h  = blockIdx.y;
    const int i0 = blockIdx.x * 64;
    const float* __restrict__ Wp   = Wt + (size_t)h * FDIM * D;
    float* __restrict__       outp = Out + (size_t)h * N_NODES * D;
    __shared__ float xs[64][33];   // +1 pad: row-reads land in distinct banks
    __shared__ float ws[32][64];
    const int t  = threadIdx.x;
    const int tr = t >> 4, tc = t & 15;
    float acc[4][4] = {{0.f}};
    for (int kt = 0; kt < FDIM; kt += 32) {
        {
            const int r = t >> 3, kk = (t & 7) << 2;
            float4 a = *(const float4*)&X[(size_t)(i0 + r) * FDIM + kt + kk];
            xs[r][kk] = a.x; xs[r][kk + 1] = a.y; xs[r][kk + 2] = a.z; xs[r][kk + 3] = a.w;
            float4 b = *(const float4*)&X[(size_t)(i0 + r + 32) * FDIM + kt + kk];
            xs[r + 32][kk] = b.x; xs[r + 32][kk + 1] = b.y; xs[r + 32][kk + 2] = b.z; xs[r + 32][kk + 3] = b.w;
            const int kw = t >> 4, c = (t & 15) << 2;
            *(float4*)&ws[kw][c]      = *(const float4*)&Wp[(size_t)(kt + kw) * D + c];
            *(float4*)&ws[kw + 16][c] = *(const float4*)&Wp[(size_t)(kt + kw + 16) * D + c];
        }
        __syncthreads();
        #pragma unroll
        for (int k = 0; k < 32; ++k) {
            float w4[4];
            *(float4*)&w4[0] = *(float4*)&ws[k][tc << 2];
            float xv[4];
            #pragma unroll
            for (int rr = 0; rr < 4; ++rr) xv[rr] = xs[tr * 4 + rr][k];
            #pragma unroll
            for (int rr = 0; rr < 4; ++rr)
                #pragma unroll
                for (int cc = 0; cc < 4; ++cc) acc[rr][cc] += xv[rr] * w4[cc];
        }
        __syncthreads();
    }
    #pragma unroll
    for (int rr = 0; rr < 4; ++rr) {
        float4 v = make_float4(acc[rr][0], acc[rr][1], acc[rr][2], acc[rr][3]);
        *(float4*)&outp[(size_t)(i0 + tr * 4 + rr) * D + (tc << 2)] = v;
    }
}

// ---------------------------------------------------------------- f = Wh . a   (one wave per row)
__global__ void k_f(const float* __restrict__ Whp, const float* __restrict__ asrc,
                    const float* __restrict__ adst, float* __restrict__ fs,
                    float* __restrict__ fd) {
    const int h    = blockIdx.y;
    const int n    = blockIdx.x * 4 + (threadIdx.x >> 6);
    const int lane = threadIdx.x & 63;
    float v  = Whp[((size_t)h * N_NODES + n) * D + lane];
    float s1 = v * asrc[h * D + lane];
    float s2 = v * adst[h * D + lane];
    #pragma unroll
    for (int off = 32; off > 0; off >>= 1) {
        s1 += __shfl_down(s1, off);
        s2 += __shfl_down(s2, off);
    }
    if (lane == 0) {
        fs[(size_t)h * N_NODES + n] = s1;
        fd[(size_t)h * N_NODES + n] = s2;
    }
}

// ---------------------------------------------------------------- masked-softmax row stats (m, 1/l)
// grid (N/64, heads); block 256: 4 threads (lane quad) per row, each scans 1024 j.
__global__ void k_stats(const unsigned long long* __restrict__ bits,
                        const float* __restrict__ fs_arr, const float* __restrict__ fd_arr,
                        float* __restrict__ m_out, float* __restrict__ linv_out) {
    const int h = blockIdx.y;
    const int i = blockIdx.x * 64 + (threadIdx.x >> 2);
    const int q = threadIdx.x & 3;
    const float fs = fs_arr[(size_t)h * N_NODES + i];
    const float* __restrict__ fd = fd_arr + (size_t)h * N_NODES;
    const unsigned long long* __restrict__ brow = bits + (size_t)i * NWORDS;
    float m = -INFINITY;
    for (int w = 0; w < 16; ++w) {
        unsigned long long word = brow[q * 16 + w];
        int jb = q * 1024 + w * 64;
        for (int b = 0; b < 64; ++b) {
            if ((word >> b) & 1ull) {
                float e = fs + fd[jb + b];
                e = fmaxf(e, 0.2f * e);      // leaky_relu, slope 0.2
                m = fmaxf(m, e);
            }
        }
    }
    m = fmaxf(m, __shfl_xor(m, 1));
    m = fmaxf(m, __shfl_xor(m, 2));
    float l = 0.f;
    for (int w = 0; w < 16; ++w) {
        unsigned long long word = brow[q * 16 + w];
        int jb = q * 1024 + w * 64;
        for (int b = 0; b < 64; ++b) {
            if ((word >> b) & 1ull) {
                float e = fs + fd[jb + b];
                e = fmaxf(e, 0.2f * e);
                l += __expf(e - m);
            }
        }
    }
    l += __shfl_xor(l, 1);
    l += __shfl_xor(l, 2);
    if (q == 0) {
        size_t o = (size_t)h * N_NODES + i;
        if (l > 0.f) { m_out[o] = m; linv_out[o] = 1.f / l; }
        else         { m_out[o] = 0.f; linv_out[o] = -1.f; }   // no edges: uniform fallback
    }
}

// ---------------------------------------------------------------- attention aggregation
// grid (N/64, heads); block 256 = 4 waves. Wave jg handles j-subgroup; lane: 4 rows x 16 d accs.
__global__ void __launch_bounds__(256) k_accum(
    const unsigned long long* __restrict__ bits,
    const float* __restrict__ Whb, const float* __restrict__ fsb,
    const float* __restrict__ fdb, const float* __restrict__ mb,
    const float* __restrict__ lib, float* __restrict__ out,
    int out_stride, int do_elu) {
    const int h  = blockIdx.y;
    const int i0 = blockIdx.x * 64;
    const float* __restrict__ Whp = Whb + (size_t)h * N_NODES * D;
    const float* __restrict__ fsp = fsb + (size_t)h * N_NODES;
    const float* __restrict__ fdp = fdb + (size_t)h * N_NODES;
    const float* __restrict__ mp  = mb  + (size_t)h * N_NODES;
    const float* __restrict__ lip = lib + (size_t)h * N_NODES;

    __shared__ float whs[64][64];          // 16 KB j-tile of Wh (reused as reduction buffer)
    __shared__ float fds[64];
    __shared__ unsigned long long aw[64];

    const int t  = threadIdx.x;
    const int jg = t >> 6;                 // wave id = j subgroup
    const int s  = t & 63;
    const int rq = s >> 2;                 // 16 row-quads
    const int dq = s & 3;                  // 4 d-groups of 16

    float fsr[4], mr[4], lir[4];
    bool uni[4];
    #pragma unroll
    for (int rr = 0; rr < 4; ++rr) {
        int r = rq * 4 + rr;
        fsr[rr] = fsp[i0 + r];
        mr[rr]  = mp[i0 + r];
        float li = lip[i0 + r];
        uni[rr] = (li < 0.f);
        lir[rr] = fabsf(li);
    }
    const float UNIP = 1.0f / (float)N_NODES;

    float acc[4][16];
    #pragma unroll
    for (int rr = 0; rr < 4; ++rr)
        #pragma unroll
        for (int k = 0; k < 16; ++k) acc[rr][k] = 0.f;

    for (int jt = 0; jt < N_NODES; jt += 64) {
        #pragma unroll
        for (int p = 0; p < 4; ++p) {      // stage Wh[h, jt:jt+64, :] (coalesced float4)
            int f = p * 256 + t;
            int r = f >> 4, c4 = (f & 15) << 2;
            *(float4*)&whs[r][c4] = *(const float4*)&Whp[(size_t)(jt + r) * D + c4];
        }
        if (t < 64) fds[t] = fdp[jt + t];
        else if (t < 128) aw[t - 64] = bits[(size_t)(i0 + t - 64) * NWORDS + (jt >> 6)];
        __syncthreads();
        unsigned long long w[4];
        #pragma unroll
        for (int rr = 0; rr < 4; ++rr) w[rr] = aw[rq * 4 + rr];
        #pragma unroll
        for (int jj = 0; jj < 16; ++jj) {
            const int jl = jg * 16 + jj;
            const float fdv = fds[jl];
            float wv[16];
            *(float4*)&wv[0]  = *(float4*)&whs[jl][dq * 16 + 0];
            *(float4*)&wv[4]  = *(float4*)&whs[jl][dq * 16 + 4];
            *(float4*)&wv[8]  = *(float4*)&whs[jl][dq * 16 + 8];
            *(float4*)&wv[12] = *(float4*)&whs[jl][dq * 16 + 12];
            #pragma unroll
            for (int rr = 0; rr < 4; ++rr) {
                float e = fsr[rr] + fdv;
                e = fmaxf(e, 0.2f * e);
                float pe = __expf(e - mr[rr]) * lir[rr];
                bool bit = (w[rr] >> jl) & 1ull;
                float p = bit ? pe : 0.f;
                if (uni[rr]) p = UNIP;
                #pragma unroll
                for (int k = 0; k < 16; ++k) acc[rr][k] += p * wv[k];
            }
        }
        __syncthreads();
    }
    // cross-wave (j-subgroup) reduction through LDS
    #pragma unroll
    for (int g = 0; g < 4; ++g) {
        if (jg == g) {
            #pragma unroll
            for (int rr = 0; rr < 4; ++rr) {
                float* dst = &whs[rq * 4 + rr][dq * 16];
                if (g == 0) {
                    #pragma unroll
                    for (int k = 0; k < 16; ++k) dst[k] = acc[rr][k];
                } else {
                    #pragma unroll
                    for (int k = 0; k < 16; ++k) dst[k] += acc[rr][k];
                }
            }
        }
        __syncthreads();
    }
    const int col0 = h * D;
    #pragma unroll
    for (int p = 0; p < 4; ++p) {
        int f = p * 256 + t;
        int r = f >> 4, c4 = (f & 15) << 2;
        float4 v = *(float4*)&whs[r][c4];
        if (do_elu) {
            v.x = v.x > 0.f ? v.x : __expf(v.x) - 1.f;
            v.y = v.y > 0.f ? v.y : __expf(v.y) - 1.f;
            v.z = v.z > 0.f ? v.z : __expf(v.z) - 1.f;
            v.w = v.w > 0.f ? v.w : __expf(v.w) - 1.f;
        }
        *(float4*)&out[(size_t)(i0 + r) * out_stride + col0 + c4] = v;
    }
}

// ---------------------------------------------------------------- elu + log_softmax over 64 dims
__global__ void k_lsm(const float* __restrict__ h2, float* __restrict__ out) {
    const int n    = blockIdx.x * 4 + (threadIdx.x >> 6);
    const int lane = threadIdx.x & 63;
    float v = h2[(size_t)n * D + lane];
    v = v > 0.f ? v : __expf(v) - 1.f;
    float mx = v;
    #pragma unroll
    for (int off = 32; off > 0; off >>= 1) mx = fmaxf(mx, __shfl_xor(mx, off));
    float ex = __expf(v - mx);
    float sum = ex;
    #pragma unroll
    for (int off = 32; off > 0; off >>= 1) sum += __shfl_xor(sum, off);
    out[(size_t)n * D + lane] = (v - mx) - __logf(sum);
}

// ----------------------------------------------------------------
extern "C" void kernel_launch(void* const* d_in, const int* in_sizes, int n_in,
                              void* d_out, int out_size, void* d_ws, size_t ws_size,
                              hipStream_t stream) {
    const float* x      = (const float*)d_in[0];
    const int*   adj    = (const int*)d_in[1];
    const float* W      = (const float*)d_in[2];
    const float* a_src  = (const float*)d_in[3];
    const float* a_dst  = (const float*)d_in[4];
    const float* W_o    = (const float*)d_in[5];
    const float* ao_src = (const float*)d_in[6];
    const float* ao_dst = (const float*)d_in[7];
    float* out = (float*)d_out;

    char* wsp = (char*)d_ws;
    size_t off = 0;
    auto alloc = [&](size_t bytes) -> void* {
        void* p = wsp + off;
        off += (bytes + 255) & ~(size_t)255;
        return p;
    };
    unsigned long long* adj_bits = (unsigned long long*)alloc((size_t)N_NODES * NWORDS * 8);
    float* Wh   = (float*)alloc((size_t)H * N_NODES * D * 4);
    float* fs1  = (float*)alloc((size_t)H * N_NODES * 4);
    float* fd1  = (float*)alloc((size_t)H * N_NODES * 4);
    float* m1   = (float*)alloc((size_t)H * N_NODES * 4);
    float* li1  = (float*)alloc((size_t)H * N_NODES * 4);
    float* hcat = (float*)alloc((size_t)N_NODES * H * D * 4);
    float* Who  = (float*)alloc((size_t)N_NODES * D * 4);
    float* fs2  = (float*)alloc((size_t)N_NODES * 4);
    float* fd2  = (float*)alloc((size_t)N_NODES * 4);
    float* m2   = (float*)alloc((size_t)N_NODES * 4);
    float* li2  = (float*)alloc((size_t)N_NODES * 4);
    float* h2   = (float*)alloc((size_t)N_NODES * D * 4);

    k_bits<<<dim3(N_NODES * N_NODES / 256), dim3(256), 0, stream>>>(adj, adj_bits);

    // layer 1 (8 heads, concat + ELU)
    k_gemm <<<dim3(N_NODES / 64, H), dim3(256), 0, stream>>>(x, W, Wh);
    k_f    <<<dim3(N_NODES / 4, H),  dim3(256), 0, stream>>>(Wh, a_src, a_dst, fs1, fd1);
    k_stats<<<dim3(N_NODES / 64, H), dim3(256), 0, stream>>>(adj_bits, fs1, fd1, m1, li1);
    k_accum<<<dim3(N_NODES / 64, H), dim3(256), 0, stream>>>(adj_bits, Wh, fs1, fd1, m1, li1,
                                                             hcat, H * D, 1);
    // layer 2 (single output head, no ELU inside attention)
    k_gemm <<<dim3(N_NODES / 64, 1), dim3(256), 0, stream>>>(hcat, W_o, Who);
    k_f    <<<dim3(N_NODES / 4, 1),  dim3(256), 0, stream>>>(Who, ao_src, ao_dst, fs2, fd2);
    k_stats<<<dim3(N_NODES / 64, 1), dim3(256), 0, stream>>>(adj_bits, fs2, fd2, m2, li2);
    k_accum<<<dim3(N_NODES / 64, 1), dim3(256), 0, stream>>>(adj_bits, Who, fs2, fd2, m2, li2,
                                                             h2, D, 0);
    // ELU + log_softmax
    k_lsm  <<<dim3(N_NODES / 4), dim3(256), 0, stream>>>(h2, out);
}

// Round 2
// 800.978 us; speedup vs baseline: 1.5821x; 1.5821x over previous
//
#include <hip/hip_runtime.h>
#include <hip/hip_bf16.h>
#include <math.h>

#define N_NODES 4096
#define FDIM 512
#define D 64
#define H 8
#define NWORDS (N_NODES / 64)   // 64 u64 words per adjacency row

typedef __attribute__((ext_vector_type(8))) short bf16x8;   // 8 bf16 = 4 VGPRs
typedef __attribute__((ext_vector_type(4))) float f32x4;

__device__ inline short f2bf(float x) {
    return (short)((__builtin_bit_cast(unsigned int, x) + 0x8000u) >> 16);
}

// ---------------------------------------------------------------- adj -> bitmask
__global__ void k_bits(const int* __restrict__ adj, unsigned long long* __restrict__ bits) {
    int idx = blockIdx.x * 256 + threadIdx.x;          // element index i*N + j
    unsigned long long m = __ballot(adj[idx] != 0);    // 64-bit wave mask
    if ((threadIdx.x & 63) == 0) bits[idx >> 6] = m;
}

// ---------------------------------------------------------------- GEMM  [N,512] @ [512,64] per head
// Writes fp32 result AND bf16 fragment-ordered copy WB[h][j>>3][d][j&7] for the MFMA consumer.
__global__ void k_gemm(const float* __restrict__ X, const float* __restrict__ Wt,
                       float* __restrict__ Out, short* __restrict__ WBout) {
    const int h  = blockIdx.y;
    const int i0 = blockIdx.x * 64;
    const float* __restrict__ Wp   = Wt + (size_t)h * FDIM * D;
    float* __restrict__       outp = Out + (size_t)h * N_NODES * D;
    short* __restrict__       wbp  = WBout + (size_t)h * (N_NODES / 8) * D * 8;
    __shared__ float xs[64][33];
    __shared__ float ws[32][64];
    const int t  = threadIdx.x;
    const int tr = t >> 4, tc = t & 15;
    float acc[4][4] = {{0.f}};
    for (int kt = 0; kt < FDIM; kt += 32) {
        {
            const int r = t >> 3, kk = (t & 7) << 2;
            float4 a = *(const float4*)&X[(size_t)(i0 + r) * FDIM + kt + kk];
            xs[r][kk] = a.x; xs[r][kk + 1] = a.y; xs[r][kk + 2] = a.z; xs[r][kk + 3] = a.w;
            float4 b = *(const float4*)&X[(size_t)(i0 + r + 32) * FDIM + kt + kk];
            xs[r + 32][kk] = b.x; xs[r + 32][kk + 1] = b.y; xs[r + 32][kk + 2] = b.z; xs[r + 32][kk + 3] = b.w;
            const int kw = t >> 4, c = (t & 15) << 2;
            *(float4*)&ws[kw][c]      = *(const float4*)&Wp[(size_t)(kt + kw) * D + c];
            *(float4*)&ws[kw + 16][c] = *(const float4*)&Wp[(size_t)(kt + kw + 16) * D + c];
        }
        __syncthreads();
        #pragma unroll
        for (int k = 0; k < 32; ++k) {
            float w4[4];
            *(float4*)&w4[0] = *(float4*)&ws[k][tc << 2];
            float xv[4];
            #pragma unroll
            for (int rr = 0; rr < 4; ++rr) xv[rr] = xs[tr * 4 + rr][k];
            #pragma unroll
            for (int rr = 0; rr < 4; ++rr)
                #pragma unroll
                for (int cc = 0; cc < 4; ++cc) acc[rr][cc] += xv[rr] * w4[cc];
        }
        __syncthreads();
    }
    #pragma unroll
    for (int rr = 0; rr < 4; ++rr) {
        const int j = i0 + tr * 4 + rr;
        float4 v = make_float4(acc[rr][0], acc[rr][1], acc[rr][2], acc[rr][3]);
        *(float4*)&outp[(size_t)j * D + (tc << 2)] = v;
        const int jb = j >> 3, jo = j & 7;
        #pragma unroll
        for (int cc = 0; cc < 4; ++cc)
            wbp[((size_t)jb * D + (tc * 4 + cc)) * 8 + jo] = f2bf(acc[rr][cc]);
    }
}

// ---------------------------------------------------------------- f = Wh . a   (one wave per row)
__global__ void k_f(const float* __restrict__ Whp, const float* __restrict__ asrc,
                    const float* __restrict__ adst, float* __restrict__ fs,
                    float* __restrict__ fd) {
    const int h    = blockIdx.y;
    const int n    = blockIdx.x * 4 + (threadIdx.x >> 6);
    const int lane = threadIdx.x & 63;
    float v  = Whp[((size_t)h * N_NODES + n) * D + lane];
    float s1 = v * asrc[h * D + lane];
    float s2 = v * adst[h * D + lane];
    #pragma unroll
    for (int off = 32; off > 0; off >>= 1) {
        s1 += __shfl_down(s1, off);
        s2 += __shfl_down(s2, off);
    }
    if (lane == 0) {
        fs[(size_t)h * N_NODES + n] = s1;
        fd[(size_t)h * N_NODES + n] = s2;
    }
}

// ---------------------------------------------------------------- per-head aux: max_j fd[j], colmean of Wh
__global__ void k_aux(const float* __restrict__ fd, const float* __restrict__ Wh,
                      float* __restrict__ gmax, float* __restrict__ colmean) {
    const int h = blockIdx.x;
    const int t = threadIdx.x;
    const int lane = t & 63;
    float m = -INFINITY;
    for (int i = t; i < N_NODES; i += 256) m = fmaxf(m, fd[(size_t)h * N_NODES + i]);
    #pragma unroll
    for (int off = 32; off > 0; off >>= 1) m = fmaxf(m, __shfl_xor(m, off));
    __shared__ float red[4];
    if (lane == 0) red[t >> 6] = m;
    // colmean partials
    const int d = t & 63, rg = t >> 6;
    const float* base = Wh + (size_t)h * N_NODES * D;
    float s = 0.f;
    for (int r = rg; r < N_NODES; r += 4) s += base[(size_t)r * D + d];
    __shared__ float cs[4][64];
    cs[rg][d] = s;
    __syncthreads();
    if (t == 0) gmax[h] = fmaxf(fmaxf(red[0], red[1]), fmaxf(red[2], red[3]));
    if (t < 64) colmean[h * D + t] = (cs[0][t] + cs[1][t] + cs[2][t] + cs[3][t]) * (1.f / (float)N_NODES);
}

// ---------------------------------------------------------------- MFMA attention aggregation
// Block = 64 i-rows x 64 d, 4 waves (wave w -> rows w*16..+15).
// A = P (attention weights) generated in registers in A-fragment layout;
// B = bf16 fragment-ordered Wh from global (L2-resident);
// 5th MFMA vs all-ones B accumulates the softmax denominator (row sums of P).
__global__ void __launch_bounds__(256) k_accum(
    const unsigned int* __restrict__ bits32,      // [N][128] u32 adjacency bits
    const short* __restrict__ WB,                 // [H][N/8][64][8] bf16 frags
    const float* __restrict__ fsb, const float* __restrict__ fdb,
    const float* __restrict__ gmaxp, const float* __restrict__ colmean,
    float* __restrict__ out, int out_stride, int do_elu) {
    const int h    = blockIdx.y;
    const int i0   = blockIdx.x * 64;
    const int t    = threadIdx.x;
    const int w    = t >> 6;
    const int lane = t & 63;
    const int li   = lane & 15;
    const int quad = lane >> 4;
    const int k0   = quad * 8;

    const int   i_row = i0 + w * 16 + li;
    const float fs    = fsb[(size_t)h * N_NODES + i_row];
    const float gm    = gmaxp[h];
    const float em    = fs + gm;
    const float m_i   = fmaxf(em, 0.2f * em);     // upper bound on leaky(fs+fd_j)
    const float* __restrict__ fd = fdb + (size_t)h * N_NODES;
    const short* __restrict__ Bh = WB + (size_t)h * (N_NODES / 8) * D * 8;
    const unsigned int* __restrict__ brow = bits32 + (size_t)i_row * (NWORDS * 2);

    f32x4 c0 = {0.f, 0.f, 0.f, 0.f}, c1 = c0, c2 = c0, c3 = c0, c5 = c0;
    bf16x8 ones;
    #pragma unroll
    for (int j = 0; j < 8; ++j) ones[j] = (short)0x3F80;   // bf16 1.0

    #pragma unroll 2
    for (int kt = 0; kt < N_NODES; kt += 32) {
        const float4 f0 = *(const float4*)&fd[kt + k0];
        const float4 f1 = *(const float4*)&fd[kt + k0 + 4];
        const unsigned int byte = (brow[kt >> 5] >> k0) & 0xFFu;
        float pv[8];
        pv[0] = f0.x; pv[1] = f0.y; pv[2] = f0.z; pv[3] = f0.w;
        pv[4] = f1.x; pv[5] = f1.y; pv[6] = f1.z; pv[7] = f1.w;
        bf16x8 a;
        #pragma unroll
        for (int j = 0; j < 8; ++j) {
            float tt = fs + pv[j];
            float e  = fmaxf(tt, 0.2f * tt);      // leaky_relu 0.2
            float pe = __expf(e - m_i);           // <= 1
            float p  = ((byte >> j) & 1u) ? pe : 0.f;
            a[j] = f2bf(p);
        }
        const short* bb = Bh + (size_t)((kt >> 3) + quad) * (D * 8) + li * 8;
        bf16x8 b0 = *(const bf16x8*)(bb);
        bf16x8 b1 = *(const bf16x8*)(bb + 128);
        bf16x8 b2 = *(const bf16x8*)(bb + 256);
        bf16x8 b3 = *(const bf16x8*)(bb + 384);
        c0 = __builtin_amdgcn_mfma_f32_16x16x32_bf16(a, b0, c0, 0, 0, 0);
        c1 = __builtin_amdgcn_mfma_f32_16x16x32_bf16(a, b1, c1, 0, 0, 0);
        c2 = __builtin_amdgcn_mfma_f32_16x16x32_bf16(a, b2, c2, 0, 0, 0);
        c3 = __builtin_amdgcn_mfma_f32_16x16x32_bf16(a, b3, c3, 0, 0, 0);
        c5 = __builtin_amdgcn_mfma_f32_16x16x32_bf16(a, ones, c5, 0, 0, 0);
    }

    // epilogue: C/D layout col=lane&15, row=quad*4+reg
    float linv[4]; bool uni[4];
    #pragma unroll
    for (int r = 0; r < 4; ++r) {
        float l = c5[r];
        uni[r]  = !(l > 0.f);
        linv[r] = uni[r] ? 0.f : 1.f / l;
    }
    const int col0 = h * D;    // layer2 has h==0 -> col0=0
    float tiles[4][4];
    #pragma unroll
    for (int r = 0; r < 4; ++r) { tiles[0][r] = c0[r]; tiles[1][r] = c1[r]; tiles[2][r] = c2[r]; tiles[3][r] = c3[r]; }
    #pragma unroll
    for (int t4 = 0; t4 < 4; ++t4) {
        #pragma unroll
        for (int r = 0; r < 4; ++r) {
            const int row = w * 16 + quad * 4 + r;
            const int d   = t4 * 16 + li;
            float v = tiles[t4][r] * linv[r];
            if (uni[r]) v = colmean[h * D + d];   // no-edge row: uniform softmax = column mean
            if (do_elu) v = v > 0.f ? v : __expf(v) - 1.f;
            out[(size_t)(i0 + row) * out_stride + col0 + d] = v;
        }
    }
}

// ---------------------------------------------------------------- elu + log_softmax over 64 dims
__global__ void k_lsm(const float* __restrict__ h2, float* __restrict__ out) {
    const int n    = blockIdx.x * 4 + (threadIdx.x >> 6);
    const int lane = threadIdx.x & 63;
    float v = h2[(size_t)n * D + lane];
    v = v > 0.f ? v : __expf(v) - 1.f;
    float mx = v;
    #pragma unroll
    for (int off = 32; off > 0; off >>= 1) mx = fmaxf(mx, __shfl_xor(mx, off));
    float ex = __expf(v - mx);
    float sum = ex;
    #pragma unroll
    for (int off = 32; off > 0; off >>= 1) sum += __shfl_xor(sum, off);
    out[(size_t)n * D + lane] = (v - mx) - __logf(sum);
}

// ----------------------------------------------------------------
extern "C" void kernel_launch(void* const* d_in, const int* in_sizes, int n_in,
                              void* d_out, int out_size, void* d_ws, size_t ws_size,
                              hipStream_t stream) {
    const float* x      = (const float*)d_in[0];
    const int*   adj    = (const int*)d_in[1];
    const float* W      = (const float*)d_in[2];
    const float* a_src  = (const float*)d_in[3];
    const float* a_dst  = (const float*)d_in[4];
    const float* W_o    = (const float*)d_in[5];
    const float* ao_src = (const float*)d_in[6];
    const float* ao_dst = (const float*)d_in[7];
    float* out = (float*)d_out;

    char* wsp = (char*)d_ws;
    size_t off = 0;
    auto alloc = [&](size_t bytes) -> void* {
        void* p = wsp + off;
        off += (bytes + 255) & ~(size_t)255;
        return p;
    };
    unsigned long long* adj_bits = (unsigned long long*)alloc((size_t)N_NODES * NWORDS * 8);
    float* Wh    = (float*)alloc((size_t)H * N_NODES * D * 4);
    short* WhB   = (short*)alloc((size_t)H * N_NODES * D * 2);
    float* fs1   = (float*)alloc((size_t)H * N_NODES * 4);
    float* fd1   = (float*)alloc((size_t)H * N_NODES * 4);
    float* gmax1 = (float*)alloc((size_t)H * 4);
    float* cm1   = (float*)alloc((size_t)H * D * 4);
    float* hcat  = (float*)alloc((size_t)N_NODES * H * D * 4);
    float* Who   = (float*)alloc((size_t)N_NODES * D * 4);
    short* WhoB  = (short*)alloc((size_t)N_NODES * D * 2);
    float* fs2   = (float*)alloc((size_t)N_NODES * 4);
    float* fd2   = (float*)alloc((size_t)N_NODES * 4);
    float* gmax2 = (float*)alloc(4);
    float* cm2   = (float*)alloc((size_t)D * 4);
    float* h2    = (float*)alloc((size_t)N_NODES * D * 4);

    const unsigned int* bits32 = (const unsigned int*)adj_bits;

    k_bits<<<dim3(N_NODES * N_NODES / 256), dim3(256), 0, stream>>>(adj, adj_bits);

    // layer 1 (8 heads, concat + ELU)
    k_gemm <<<dim3(N_NODES / 64, H), dim3(256), 0, stream>>>(x, W, Wh, WhB);
    k_f    <<<dim3(N_NODES / 4, H),  dim3(256), 0, stream>>>(Wh, a_src, a_dst, fs1, fd1);
    k_aux  <<<dim3(H), dim3(256), 0, stream>>>(fd1, Wh, gmax1, cm1);
    k_accum<<<dim3(N_NODES / 64, H), dim3(256), 0, stream>>>(bits32, WhB, fs1, fd1, gmax1, cm1,
                                                             hcat, H * D, 1);
    // layer 2 (single output head, no ELU inside attention)
    k_gemm <<<dim3(N_NODES / 64, 1), dim3(256), 0, stream>>>(hcat, W_o, Who, WhoB);
    k_f    <<<dim3(N_NODES / 4, 1),  dim3(256), 0, stream>>>(Who, ao_src, ao_dst, fs2, fd2);
    k_aux  <<<dim3(1), dim3(256), 0, stream>>>(fd2, Who, gmax2, cm2);
    k_accum<<<dim3(N_NODES / 64, 1), dim3(256), 0, stream>>>(bits32, WhoB, fs2, fd2, gmax2, cm2,
                                                             h2, D, 0);
    // ELU + log_softmax
    k_lsm  <<<dim3(N_NODES / 4), dim3(256), 0, stream>>>(h2, out);
}

// Round 3
// 350.601 us; speedup vs baseline: 3.6144x; 2.2846x over previous
//
#include <hip/hip_runtime.h>
#include <hip/hip_bf16.h>
#include <math.h>

#define N_NODES 4096
#define FDIM 512
#define D 64
#define H 8
#define NWORDS (N_NODES / 64)   // 64 u64 words per adjacency row

typedef __attribute__((ext_vector_type(8))) short bf16x8;   // 8 bf16 = 4 VGPRs
typedef __attribute__((ext_vector_type(4))) float f32x4;

__device__ inline short f2bf(float x) {
    return (short)((__builtin_bit_cast(unsigned int, x) + 0x8000u) >> 16);
}

// ---------------------------------------------------------------- adj -> bitmask
__global__ void k_bits(const int* __restrict__ adj, unsigned long long* __restrict__ bits) {
    int idx = blockIdx.x * 256 + threadIdx.x;          // element index i*N + j
    unsigned long long m = __ballot(adj[idx] != 0);    // 64-bit wave mask
    if ((threadIdx.x & 63) == 0) bits[idx >> 6] = m;
}

// ---------------------------------------------------------------- GEMM  [N,512] @ [512,64] per head
// Writes fp32 result AND bf16 fragment-ordered copy WB[h][j>>3][d][j&7] for the MFMA consumer.
__global__ void k_gemm(const float* __restrict__ X, const float* __restrict__ Wt,
                       float* __restrict__ Out, short* __restrict__ WBout) {
    const int h  = blockIdx.y;
    const int i0 = blockIdx.x * 64;
    const float* __restrict__ Wp   = Wt + (size_t)h * FDIM * D;
    float* __restrict__       outp = Out + (size_t)h * N_NODES * D;
    short* __restrict__       wbp  = WBout + (size_t)h * (N_NODES / 8) * D * 8;
    __shared__ float xs[64][33];
    __shared__ float ws[32][64];
    const int t  = threadIdx.x;
    const int tr = t >> 4, tc = t & 15;
    float acc[4][4] = {{0.f}};
    for (int kt = 0; kt < FDIM; kt += 32) {
        {
            const int r = t >> 3, kk = (t & 7) << 2;
            float4 a = *(const float4*)&X[(size_t)(i0 + r) * FDIM + kt + kk];
            xs[r][kk] = a.x; xs[r][kk + 1] = a.y; xs[r][kk + 2] = a.z; xs[r][kk + 3] = a.w;
            float4 b = *(const float4*)&X[(size_t)(i0 + r + 32) * FDIM + kt + kk];
            xs[r + 32][kk] = b.x; xs[r + 32][kk + 1] = b.y; xs[r + 32][kk + 2] = b.z; xs[r + 32][kk + 3] = b.w;
            const int kw = t >> 4, c = (t & 15) << 2;
            *(float4*)&ws[kw][c]      = *(const float4*)&Wp[(size_t)(kt + kw) * D + c];
            *(float4*)&ws[kw + 16][c] = *(const float4*)&Wp[(size_t)(kt + kw + 16) * D + c];
        }
        __syncthreads();
        #pragma unroll
        for (int k = 0; k < 32; ++k) {
            float w4[4];
            *(float4*)&w4[0] = *(float4*)&ws[k][tc << 2];
            float xv[4];
            #pragma unroll
            for (int rr = 0; rr < 4; ++rr) xv[rr] = xs[tr * 4 + rr][k];
            #pragma unroll
            for (int rr = 0; rr < 4; ++rr)
                #pragma unroll
                for (int cc = 0; cc < 4; ++cc) acc[rr][cc] += xv[rr] * w4[cc];
        }
        __syncthreads();
    }
    #pragma unroll
    for (int rr = 0; rr < 4; ++rr) {
        const int j = i0 + tr * 4 + rr;
        float4 v = make_float4(acc[rr][0], acc[rr][1], acc[rr][2], acc[rr][3]);
        *(float4*)&outp[(size_t)j * D + (tc << 2)] = v;
        const int jb = j >> 3, jo = j & 7;
        #pragma unroll
        for (int cc = 0; cc < 4; ++cc)
            wbp[((size_t)jb * D + (tc * 4 + cc)) * 8 + jo] = f2bf(acc[rr][cc]);
    }
}

// ---------------------------------------------------------------- f = Wh . a   (one wave per row)
__global__ void k_f(const float* __restrict__ Whp, const float* __restrict__ asrc,
                    const float* __restrict__ adst, float* __restrict__ fs,
                    float* __restrict__ fd) {
    const int h    = blockIdx.y;
    const int n    = blockIdx.x * 4 + (threadIdx.x >> 6);
    const int lane = threadIdx.x & 63;
    float v  = Whp[((size_t)h * N_NODES + n) * D + lane];
    float s1 = v * asrc[h * D + lane];
    float s2 = v * adst[h * D + lane];
    #pragma unroll
    for (int off = 32; off > 0; off >>= 1) {
        s1 += __shfl_down(s1, off);
        s2 += __shfl_down(s2, off);
    }
    if (lane == 0) {
        fs[(size_t)h * N_NODES + n] = s1;
        fd[(size_t)h * N_NODES + n] = s2;
    }
}

// ---------------------------------------------------------------- global max of fd per head
// grid (H), block 1024: 4 loads/thread, shuffle + LDS tree. ~2 us.
__global__ void k_gmax(const float* __restrict__ fd, float* __restrict__ gmax) {
    const int h = blockIdx.x;
    const int t = threadIdx.x;
    float m = -INFINITY;
    #pragma unroll
    for (int i = 0; i < 4; ++i) m = fmaxf(m, fd[(size_t)h * N_NODES + t + i * 1024]);
    #pragma unroll
    for (int off = 32; off > 0; off >>= 1) m = fmaxf(m, __shfl_xor(m, off));
    __shared__ float red[16];
    if ((t & 63) == 0) red[t >> 6] = m;
    __syncthreads();
    if (t == 0) {
        float r = red[0];
        #pragma unroll
        for (int i = 1; i < 16; ++i) r = fmaxf(r, red[i]);
        gmax[h] = r;
    }
}

// ---------------------------------------------------------------- column mean of Wh per head
// grid (16, H), block 256: block sums 256 rows (coalesced), LDS reduce, atomicAdd per column.
// colmean buffer must be zeroed beforehand (hipMemsetAsync).
__global__ void k_colmean(const float* __restrict__ Wh, float* __restrict__ colmean) {
    const int h  = blockIdx.y;
    const int i0 = blockIdx.x * 256;
    const int t  = threadIdx.x;
    const int d  = t & 63, rg = t >> 6;
    const float* __restrict__ base = Wh + (size_t)h * N_NODES * D;
    float s = 0.f;
    #pragma unroll 8
    for (int r = rg; r < 256; r += 4) s += base[(size_t)(i0 + r) * D + d];
    __shared__ float cs[4][64];
    cs[rg][d] = s;
    __syncthreads();
    if (t < 64)
        atomicAdd(&colmean[h * D + t],
                  (cs[0][t] + cs[1][t] + cs[2][t] + cs[3][t]) * (1.f / (float)N_NODES));
}

// ---------------------------------------------------------------- MFMA attention aggregation
// Block = 64 i-rows x 64 d, 4 waves (wave w -> rows w*16..+15).
// A = P (attention weights) generated in registers in A-fragment layout;
// B = bf16 fragment-ordered Wh from global (L2-resident);
// 5th MFMA vs all-ones B accumulates the softmax denominator (row sums of P).
__global__ void __launch_bounds__(256) k_accum(
    const unsigned int* __restrict__ bits32,      // [N][128] u32 adjacency bits
    const short* __restrict__ WB,                 // [H][N/8][64][8] bf16 frags
    const float* __restrict__ fsb, const float* __restrict__ fdb,
    const float* __restrict__ gmaxp, const float* __restrict__ colmean,
    float* __restrict__ out, int out_stride, int do_elu) {
    const int h    = blockIdx.y;
    const int i0   = blockIdx.x * 64;
    const int t    = threadIdx.x;
    const int w    = t >> 6;
    const int lane = t & 63;
    const int li   = lane & 15;
    const int quad = lane >> 4;
    const int k0   = quad * 8;

    const int   i_row = i0 + w * 16 + li;
    const float fs    = fsb[(size_t)h * N_NODES + i_row];
    const float gm    = gmaxp[h];
    const float em    = fs + gm;
    const float m_i   = fmaxf(em, 0.2f * em);     // upper bound on leaky(fs+fd_j)
    const float* __restrict__ fd = fdb + (size_t)h * N_NODES;
    const short* __restrict__ Bh = WB + (size_t)h * (N_NODES / 8) * D * 8;
    const unsigned int* __restrict__ brow = bits32 + (size_t)i_row * (NWORDS * 2);

    f32x4 c0 = {0.f, 0.f, 0.f, 0.f}, c1 = c0, c2 = c0, c3 = c0, c5 = c0;
    bf16x8 ones;
    #pragma unroll
    for (int j = 0; j < 8; ++j) ones[j] = (short)0x3F80;   // bf16 1.0

    #pragma unroll 2
    for (int kt = 0; kt < N_NODES; kt += 32) {
        const float4 f0 = *(const float4*)&fd[kt + k0];
        const float4 f1 = *(const float4*)&fd[kt + k0 + 4];
        const unsigned int byte = (brow[kt >> 5] >> k0) & 0xFFu;
        float pv[8];
        pv[0] = f0.x; pv[1] = f0.y; pv[2] = f0.z; pv[3] = f0.w;
        pv[4] = f1.x; pv[5] = f1.y; pv[6] = f1.z; pv[7] = f1.w;
        bf16x8 a;
        #pragma unroll
        for (int j = 0; j < 8; ++j) {
            float tt = fs + pv[j];
            float e  = fmaxf(tt, 0.2f * tt);      // leaky_relu 0.2
            float pe = __expf(e - m_i);           // <= 1
            float p  = ((byte >> j) & 1u) ? pe : 0.f;
            a[j] = f2bf(p);
        }
        const short* bb = Bh + (size_t)((kt >> 3) + quad) * (D * 8) + li * 8;
        bf16x8 b0 = *(const bf16x8*)(bb);
        bf16x8 b1 = *(const bf16x8*)(bb + 128);
        bf16x8 b2 = *(const bf16x8*)(bb + 256);
        bf16x8 b3 = *(const bf16x8*)(bb + 384);
        c0 = __builtin_amdgcn_mfma_f32_16x16x32_bf16(a, b0, c0, 0, 0, 0);
        c1 = __builtin_amdgcn_mfma_f32_16x16x32_bf16(a, b1, c1, 0, 0, 0);
        c2 = __builtin_amdgcn_mfma_f32_16x16x32_bf16(a, b2, c2, 0, 0, 0);
        c3 = __builtin_amdgcn_mfma_f32_16x16x32_bf16(a, b3, c3, 0, 0, 0);
        c5 = __builtin_amdgcn_mfma_f32_16x16x32_bf16(a, ones, c5, 0, 0, 0);
    }

    // epilogue: C/D layout col=lane&15, row=quad*4+reg
    float linv[4]; bool uni[4];
    #pragma unroll
    for (int r = 0; r < 4; ++r) {
        float l = c5[r];
        uni[r]  = !(l > 0.f);
        linv[r] = uni[r] ? 0.f : 1.f / l;
    }
    const int col0 = h * D;    // layer2 has h==0 -> col0=0
    float tiles[4][4];
    #pragma unroll
    for (int r = 0; r < 4; ++r) { tiles[0][r] = c0[r]; tiles[1][r] = c1[r]; tiles[2][r] = c2[r]; tiles[3][r] = c3[r]; }
    #pragma unroll
    for (int t4 = 0; t4 < 4; ++t4) {
        #pragma unroll
        for (int r = 0; r < 4; ++r) {
            const int row = w * 16 + quad * 4 + r;
            const int d   = t4 * 16 + li;
            float v = tiles[t4][r] * linv[r];
            if (uni[r]) v = colmean[h * D + d];   // no-edge row: uniform softmax = column mean
            if (do_elu) v = v > 0.f ? v : __expf(v) - 1.f;
            out[(size_t)(i0 + row) * out_stride + col0 + d] = v;
        }
    }
}

// ---------------------------------------------------------------- elu + log_softmax over 64 dims
__global__ void k_lsm(const float* __restrict__ h2, float* __restrict__ out) {
    const int n    = blockIdx.x * 4 + (threadIdx.x >> 6);
    const int lane = threadIdx.x & 63;
    float v = h2[(size_t)n * D + lane];
    v = v > 0.f ? v : __expf(v) - 1.f;
    float mx = v;
    #pragma unroll
    for (int off = 32; off > 0; off >>= 1) mx = fmaxf(mx, __shfl_xor(mx, off));
    float ex = __expf(v - mx);
    float sum = ex;
    #pragma unroll
    for (int off = 32; off > 0; off >>= 1) sum += __shfl_xor(sum, off);
    out[(size_t)n * D + lane] = (v - mx) - __logf(sum);
}

// ----------------------------------------------------------------
extern "C" void kernel_launch(void* const* d_in, const int* in_sizes, int n_in,
                              void* d_out, int out_size, void* d_ws, size_t ws_size,
                              hipStream_t stream) {
    const float* x      = (const float*)d_in[0];
    const int*   adj    = (const int*)d_in[1];
    const float* W      = (const float*)d_in[2];
    const float* a_src  = (const float*)d_in[3];
    const float* a_dst  = (const float*)d_in[4];
    const float* W_o    = (const float*)d_in[5];
    const float* ao_src = (const float*)d_in[6];
    const float* ao_dst = (const float*)d_in[7];
    float* out = (float*)d_out;

    char* wsp = (char*)d_ws;
    size_t off = 0;
    auto alloc = [&](size_t bytes) -> void* {
        void* p = wsp + off;
        off += (bytes + 255) & ~(size_t)255;
        return p;
    };
    unsigned long long* adj_bits = (unsigned long long*)alloc((size_t)N_NODES * NWORDS * 8);
    float* Wh    = (float*)alloc((size_t)H * N_NODES * D * 4);
    short* WhB   = (short*)alloc((size_t)H * N_NODES * D * 2);
    float* fs1   = (float*)alloc((size_t)H * N_NODES * 4);
    float* fd1   = (float*)alloc((size_t)H * N_NODES * 4);
    float* gmax1 = (float*)alloc((size_t)H * 4);
    float* cm1   = (float*)alloc((size_t)H * D * 4);
    float* hcat  = (float*)alloc((size_t)N_NODES * H * D * 4);
    float* Who   = (float*)alloc((size_t)N_NODES * D * 4);
    short* WhoB  = (short*)alloc((size_t)N_NODES * D * 2);
    float* fs2   = (float*)alloc((size_t)N_NODES * 4);
    float* fd2   = (float*)alloc((size_t)N_NODES * 4);
    float* gmax2 = (float*)alloc(4);
    float* cm2   = (float*)alloc((size_t)D * 4);
    float* h2    = (float*)alloc((size_t)N_NODES * D * 4);

    const unsigned int* bits32 = (const unsigned int*)adj_bits;

    // zero the atomic-accumulated colmean buffers (graph-capture-safe)
    hipMemsetAsync(cm1, 0, (size_t)H * D * 4, stream);
    hipMemsetAsync(cm2, 0, (size_t)D * 4, stream);

    k_bits<<<dim3(N_NODES * N_NODES / 256), dim3(256), 0, stream>>>(adj, adj_bits);

    // layer 1 (8 heads, concat + ELU)
    k_gemm   <<<dim3(N_NODES / 64, H), dim3(256), 0, stream>>>(x, W, Wh, WhB);
    k_f      <<<dim3(N_NODES / 4, H),  dim3(256), 0, stream>>>(Wh, a_src, a_dst, fs1, fd1);
    k_gmax   <<<dim3(H), dim3(1024), 0, stream>>>(fd1, gmax1);
    k_colmean<<<dim3(16, H), dim3(256), 0, stream>>>(Wh, cm1);
    k_accum  <<<dim3(N_NODES / 64, H), dim3(256), 0, stream>>>(bits32, WhB, fs1, fd1, gmax1, cm1,
                                                               hcat, H * D, 1);
    // layer 2 (single output head, no ELU inside attention)
    k_gemm   <<<dim3(N_NODES / 64, 1), dim3(256), 0, stream>>>(hcat, W_o, Who, WhoB);
    k_f      <<<dim3(N_NODES / 4, 1),  dim3(256), 0, stream>>>(Who, ao_src, ao_dst, fs2, fd2);
    k_gmax   <<<dim3(1), dim3(1024), 0, stream>>>(fd2, gmax2);
    k_colmean<<<dim3(16, 1), dim3(256), 0, stream>>>(Who, cm2);
    k_accum  <<<dim3(N_NODES / 64, 1), dim3(256), 0, stream>>>(bits32, WhoB, fs2, fd2, gmax2, cm2,
                                                               h2, D, 0);
    // ELU + log_softmax
    k_lsm    <<<dim3(N_NODES / 4), dim3(256), 0, stream>>>(h2, out);
}